// Round 1
// baseline (185.055 us; speedup 1.0000x reference)
//
#include <hip/hip_runtime.h>

// Packed-sequence LSTM (B=4096, T=512, D=18, H=8) + Linear(8->1) head.
//
// Structure: latency-bound recurrence. 16 lanes per sequence, 4 sequences per
// wave64, grid = 1024 one-wave blocks -> exactly 1 wave per SIMD (1024 SIMDs),
// so the wave carrying the longest sequences never shares issue slots.
// Lane (p, j): p = half (0/1), j = hidden unit. p=0 computes gates {i, g},
// p=1 computes {f, o}; two shfl_xor(8) exchanges let both halves redundantly
// hold c[j], h[j]. Full h is kept replicated per-lane (8 VGPRs), refreshed
// with 8 __shfl per step (also feeds the linear head).
// x rows prefetched 4 steps deep (9x float2 per row) to cover HBM latency.

namespace {

constexpr int NB = 4096;
constexpr int NT = 512;
constexpr int ND = 18;
constexpr int NH = 8;

__device__ __forceinline__ float fsig(float x) {
    // sigmoid(x) = 1 / (1 + e^-x); v_mul+v_exp+v_add+v_rcp
    return __builtin_amdgcn_rcpf(1.0f + __expf(-x));
}
__device__ __forceinline__ float ftanh(float x) {
    // tanh(x) = 1 - 2/(e^{2x}+1); saturates correctly at +/-inf
    return fmaf(-2.0f, __builtin_amdgcn_rcpf(1.0f + __expf(x + x)), 1.0f);
}

__global__ __launch_bounds__(64, 1) void lstm_packed(
    const float* __restrict__ x, const int* __restrict__ lengths,
    const float* __restrict__ W_ih, const float* __restrict__ W_hh,
    const float* __restrict__ b_ih, const float* __restrict__ b_hh,
    const float* __restrict__ W_lin, const float* __restrict__ b_lin,
    float* __restrict__ out)
{
    const int w   = (int)threadIdx.x;   // 0..63
    const int grp = w >> 4;             // 4 sequences per wave
    const int l16 = w & 15;
    const int p   = l16 >> 3;           // half: 0 -> {i,g}, 1 -> {f,o}
    const int j   = l16 & 7;            // hidden unit
    const int b   = (int)blockIdx.x * 4 + grp;
    const int len = lengths[b];

    // torch gate order: rows [0:8)=i [8:16)=f [16:24)=g [24:32)=o
    const int rowA = j + (p ? 8 : 0);    // p0: i-row,  p1: f-row
    const int rowB = j + (p ? 24 : 16);  // p0: g-row,  p1: o-row

    float wihA[ND], wihB[ND];
#pragma unroll
    for (int k = 0; k < ND; ++k) {
        wihA[k] = W_ih[rowA * ND + k];
        wihB[k] = W_ih[rowB * ND + k];
    }
    float whhA[NH], whhB[NH];
#pragma unroll
    for (int k = 0; k < NH; ++k) {
        whhA[k] = W_hh[rowA * NH + k];
        whhB[k] = W_hh[rowB * NH + k];
    }
    const float biasA = b_ih[rowA] + b_hh[rowA];
    const float biasB = b_ih[rowB] + b_hh[rowB];
    float wl[NH];
#pragma unroll
    for (int k = 0; k < NH; ++k) wl[k] = W_lin[k];
    const float bl = b_lin[0];

    float h_all[NH];  // replicated h_t
#pragma unroll
    for (int k = 0; k < NH; ++k) h_all[k] = 0.0f;
    float c = 0.0f, hown = 0.0f;

    const float* xb = x + (size_t)b * (NT * ND);
    float* yb = out + (size_t)b * NT;

    // 4-deep x prefetch: row t -> 9 aligned float2 (72B, stride 72B)
    float2 xf0[9], xf1[9], xf2[9], xf3[9];
    {
        const float2* r0 = (const float2*)(xb + 0 * ND);
        const float2* r1 = (const float2*)(xb + 1 * ND);
        const float2* r2 = (const float2*)(xb + 2 * ND);
        const float2* r3 = (const float2*)(xb + 3 * ND);
#pragma unroll
        for (int k = 0; k < 9; ++k) { xf0[k] = r0[k]; xf1[k] = r1[k]; xf2[k] = r2[k]; xf3[k] = r3[k]; }
    }

    for (int t = 0; t < len; t += 4) {
#pragma unroll
        for (int s = 0; s < 4; ++s) {
            const int tt = t + s;
            const bool act = tt < len;

            // consume buffer s (register copies get renamed away)
            float2 xc[9];
#pragma unroll
            for (int k = 0; k < 9; ++k)
                xc[k] = (s == 0) ? xf0[k] : (s == 1) ? xf1[k] : (s == 2) ? xf2[k] : xf3[k];

            // refill buffer s with row tt+4 (clamped; x is [B,512,18] so always in-bounds)
            {
                int r4 = tt + 4;
                r4 = (r4 < NT) ? r4 : (NT - 1);
                const float2* r = (const float2*)(xb + r4 * ND);
#pragma unroll
                for (int k = 0; k < 9; ++k) {
                    float2 v = r[k];
                    if (s == 0) xf0[k] = v; else if (s == 1) xf1[k] = v;
                    else if (s == 2) xf2[k] = v; else xf3[k] = v;
                }
            }

            // gate pre-activations: bias + x.W_ih^T + h.W_hh^T
            float aA = biasA, aB = biasB;
#pragma unroll
            for (int k = 0; k < 9; ++k) {
                aA = fmaf(xc[k].x, wihA[2 * k], aA);
                aA = fmaf(xc[k].y, wihA[2 * k + 1], aA);
                aB = fmaf(xc[k].x, wihB[2 * k], aB);
                aB = fmaf(xc[k].y, wihB[2 * k + 1], aB);
            }
#pragma unroll
            for (int k = 0; k < NH; ++k) {
                aA = fmaf(h_all[k], whhA[k], aA);
                aB = fmaf(h_all[k], whhB[k], aB);
            }

            // activations: vA = sigma(aA) (i or f). vB: p0 tanh(g)=2*sigma(2g)-1, p1 sigma(o)
            const float vA   = fsig(aA);
            const float argB = p ? aB : (aB + aB);
            const float sb   = fsig(argB);
            const float vB   = p ? sb : fmaf(2.0f, sb, -1.0f);

            // exchange across halves: p0 sends i*g, p1 sends f
            const float send1 = p ? vA : (vA * vB);
            const float recv1 = __shfl_xor(send1, 8, 64);
            const float f_ = p ? vA : recv1;
            const float ig = p ? recv1 : send1;
            const float cn = fmaf(f_, c, ig);
            c = act ? cn : c;                       // freeze state past length
            const float tc = ftanh(c);
            const float recv2 = __shfl_xor(vB, 8, 64);  // p0 receives o
            const float o_ = p ? vB : recv2;
            const float hnew = o_ * tc;
            hown = act ? hnew : hown;

            // re-replicate h_t across the 16 lanes (sources within own 8-half)
#pragma unroll
            for (int k = 0; k < NH; ++k)
                h_all[k] = __shfl(hown, (w & 56) | k, 64);

            // linear head (redundant in all lanes; one lane stores)
            float y = bl;
#pragma unroll
            for (int k = 0; k < NH; ++k) y = fmaf(h_all[k], wl[k], y);
            if (act && l16 == 0) yb[tt] = y;
        }
    }
}

} // namespace

extern "C" void kernel_launch(void* const* d_in, const int* in_sizes, int n_in,
                              void* d_out, int out_size, void* d_ws, size_t ws_size,
                              hipStream_t stream) {
    const float* x     = (const float*)d_in[0];
    const int*   lens  = (const int*)d_in[1];
    const float* W_ih  = (const float*)d_in[2];
    const float* W_hh  = (const float*)d_in[3];
    const float* b_ih  = (const float*)d_in[4];
    const float* b_hh  = (const float*)d_in[5];
    const float* W_lin = (const float*)d_in[6];
    const float* b_lin = (const float*)d_in[7];
    float* out = (float*)d_out;

    // zero the padded region (kernel only writes t < len)
    hipMemsetAsync(out, 0, (size_t)NB * NT * sizeof(float), stream);

    lstm_packed<<<NB / 4, 64, 0, stream>>>(x, lens, W_ih, W_hh, b_ih, b_hh,
                                           W_lin, b_lin, out);
}